// Round 1
// baseline (584.137 us; speedup 1.0000x reference)
//
#include <hip/hip_runtime.h>

// Problem constants (from reference setup_inputs): V=512, B=256, L=40.
constexpr int V = 512;
constexpr int B = 256;
constexpr int L = 40;
constexpr int ROWS = B * (L - 1);            // 9984 softmax rows
constexpr int WAVES_PER_BLOCK = 4;           // block = 256 threads
constexpr int BLOCKS = 624;                  // 2496 waves -> 4 rows/wave
constexpr int TOTAL_WAVES = BLOCKS * WAVES_PER_BLOCK;

__global__ __launch_bounds__(256)
void pers_nll_kernel(const int* __restrict__ seq,
                     const float* __restrict__ sim,
                     const float* __restrict__ pers,
                     const float* __restrict__ wts,
                     float* __restrict__ out)
{
    const int lane        = threadIdx.x & 63;
    const int waveInBlock = threadIdx.x >> 6;
    const int w           = blockIdx.x * WAVES_PER_BLOCK + waveInBlock;

    const float w0 = wts[0];
    const float w1 = wts[1];

    float acc = 0.0f;

    for (int r = w; r < ROWS; r += TOTAL_WAVES) {
        const int b = r / (L - 1);
        const int t = r - b * (L - 1);          // position in [0, L-2]
        const int prev = seq[b * L + t];        // row of sim_mat
        const int tgt  = seq[b * L + t + 1];    // target vocab index

        const int base = lane * 8;              // 8 consecutive f32 per lane
        const float4 s0 = *reinterpret_cast<const float4*>(sim + (size_t)prev * V + base);
        const float4 s1 = *reinterpret_cast<const float4*>(sim + (size_t)prev * V + base + 4);

        float v[8] = { s0.x, s0.y, s0.z, s0.w, s1.x, s1.y, s1.z, s1.w };
        #pragma unroll
        for (int j = 0; j < 8; ++j) v[j] *= w0;

        if (t >= 1) {
            const int p0 = seq[b * L + t - 1];
            const size_t prow = ((size_t)p0 * V + (size_t)prev) * (size_t)V;
            const float4 q0 = *reinterpret_cast<const float4*>(pers + prow + base);
            const float4 q1 = *reinterpret_cast<const float4*>(pers + prow + base + 4);
            v[0] = fmaf(w1, q0.x, v[0]); v[1] = fmaf(w1, q0.y, v[1]);
            v[2] = fmaf(w1, q0.z, v[2]); v[3] = fmaf(w1, q0.w, v[3]);
            v[4] = fmaf(w1, q1.x, v[4]); v[5] = fmaf(w1, q1.y, v[5]);
            v[6] = fmaf(w1, q1.z, v[6]); v[7] = fmaf(w1, q1.w, v[7]);
        }

        // wave-wide max (butterfly -> uniform across all 64 lanes)
        float m = v[0];
        #pragma unroll
        for (int j = 1; j < 8; ++j) m = fmaxf(m, v[j]);
        #pragma unroll
        for (int off = 32; off >= 1; off >>= 1)
            m = fmaxf(m, __shfl_xor(m, off, 64));

        // wave-wide sum of exp(v - m)
        float s = 0.0f;
        #pragma unroll
        for (int j = 0; j < 8; ++j) s += __expf(v[j] - m);
        #pragma unroll
        for (int off = 32; off >= 1; off >>= 1)
            s += __shfl_xor(s, off, 64);

        // target logit: lane (tgt>>3) holds element (tgt&7); both are wave-uniform
        const float cand = v[tgt & 7];
        const float lt   = __shfl(cand, tgt >> 3, 64);

        acc += m + __logf(s) - lt;   // -log_softmax at target
    }

    // acc is wave-uniform (butterfly reductions) -> lane 0 representative
    __shared__ float part[WAVES_PER_BLOCK];
    if (lane == 0) part[waveInBlock] = acc;
    __syncthreads();
    if (threadIdx.x == 0) {
        float total = part[0] + part[1] + part[2] + part[3];
        if (blockIdx.x == 0) total += (float)B * logf((float)V);  // nll0
        atomicAdd(out, total);
    }
}

extern "C" void kernel_launch(void* const* d_in, const int* in_sizes, int n_in,
                              void* d_out, int out_size, void* d_ws, size_t ws_size,
                              hipStream_t stream)
{
    const int*   seq  = (const int*)d_in[0];
    const float* sim  = (const float*)d_in[1];
    const float* pers = (const float*)d_in[2];
    const float* wts  = (const float*)d_in[3];
    float* out = (float*)d_out;

    // d_out is poisoned to 0xAA before every timed launch; zero it on-stream.
    hipMemsetAsync(out, 0, sizeof(float), stream);
    pers_nll_kernel<<<BLOCKS, 256, 0, stream>>>(seq, sim, pers, wts, out);
}

// Round 2
// 578.668 us; speedup vs baseline: 1.0095x; 1.0095x over previous
//
#include <hip/hip_runtime.h>

// Problem constants (from reference setup_inputs): V=512, B=256, L=40.
constexpr int V = 512;
constexpr int B = 256;
constexpr int L = 40;
constexpr int ROWS = B * (L - 1);            // 9984 softmax rows
constexpr int WPB = 4;                        // waves per 256-thread block
constexpr int BLOCKS = 624;
constexpr int TOTAL_WAVES = BLOCKS * WPB;     // 2496
constexpr int ITERS = ROWS / TOTAL_WAVES;     // exactly 4 (2496*4 == 9984)

// Note: TOTAL_WAVES = 2496 = 64 * 39, so for wave w the rows r_k = w + 2496k
// all share t = w % 39 and have b_k = w/39 + 64k. t is wave-invariant =>
// the pers branch is loop-invariant and the div/mod happens once.

__global__ __launch_bounds__(256)
void nll_main(const int* __restrict__ seq,
              const float* __restrict__ sim,
              const float* __restrict__ pers,
              const float* __restrict__ wts,
              float* __restrict__ partial)
{
    const int lane = threadIdx.x & 63;
    const int wib  = threadIdx.x >> 6;
    const int w    = blockIdx.x * WPB + wib;   // wave id in [0, 2496)

    const float w0 = wts[0];
    const float w1 = wts[1];

    const int t  = w % 39;                     // position in [0, 38]
    const int b0 = w / 39;                     // batch base in [0, 64)
    const int base = lane * 8;                 // 8 consecutive f32 per lane

    // Gather all index triples first (seq is 40 KB -> L1/L2 resident).
    int prevI[ITERS], tgtI[ITERS], p0I[ITERS];
    #pragma unroll
    for (int k = 0; k < ITERS; ++k) {
        const int off = (b0 + 64 * k) * L + t;
        prevI[k] = seq[off];
        tgtI[k]  = seq[off + 1];
        p0I[k]   = (t >= 1) ? seq[off - 1] : 0;
    }

    // Issue all row loads (4 rows x 2 float4 each for sim and pers) so the
    // cold-HBM latency of the random pers rows overlaps within the wave.
    float v[ITERS][8];
    if (t >= 1) {
        #pragma unroll
        for (int k = 0; k < ITERS; ++k) {
            const float* srow = sim + (size_t)prevI[k] * V + base;
            const float* prow = pers + ((size_t)p0I[k] * V + (size_t)prevI[k]) * V + base;
            const float4 s0 = *(const float4*)(srow);
            const float4 s1 = *(const float4*)(srow + 4);
            const float4 q0 = *(const float4*)(prow);
            const float4 q1 = *(const float4*)(prow + 4);
            v[k][0] = fmaf(w1, q0.x, w0 * s0.x);
            v[k][1] = fmaf(w1, q0.y, w0 * s0.y);
            v[k][2] = fmaf(w1, q0.z, w0 * s0.z);
            v[k][3] = fmaf(w1, q0.w, w0 * s0.w);
            v[k][4] = fmaf(w1, q1.x, w0 * s1.x);
            v[k][5] = fmaf(w1, q1.y, w0 * s1.y);
            v[k][6] = fmaf(w1, q1.z, w0 * s1.z);
            v[k][7] = fmaf(w1, q1.w, w0 * s1.w);
        }
    } else {
        #pragma unroll
        for (int k = 0; k < ITERS; ++k) {
            const float* srow = sim + (size_t)prevI[k] * V + base;
            const float4 s0 = *(const float4*)(srow);
            const float4 s1 = *(const float4*)(srow + 4);
            v[k][0] = w0 * s0.x; v[k][1] = w0 * s0.y;
            v[k][2] = w0 * s0.z; v[k][3] = w0 * s0.w;
            v[k][4] = w0 * s1.x; v[k][5] = w0 * s1.y;
            v[k][6] = w0 * s1.z; v[k][7] = w0 * s1.w;
        }
    }

    // Per-row online softmax NLL; the 4 butterfly chains are independent (ILP).
    float acc = 0.0f;
    #pragma unroll
    for (int k = 0; k < ITERS; ++k) {
        float m = v[k][0];
        #pragma unroll
        for (int j = 1; j < 8; ++j) m = fmaxf(m, v[k][j]);
        #pragma unroll
        for (int off = 32; off >= 1; off >>= 1)
            m = fmaxf(m, __shfl_xor(m, off, 64));

        float s = 0.0f;
        #pragma unroll
        for (int j = 0; j < 8; ++j) s += __expf(v[k][j] - m);
        #pragma unroll
        for (int off = 32; off >= 1; off >>= 1)
            s += __shfl_xor(s, off, 64);

        // target logit: lane (tgt>>3) holds element (tgt&7), both wave-uniform
        const float cand = v[k][tgtI[k] & 7];
        const float lt   = __shfl(cand, tgtI[k] >> 3, 64);

        acc += m + __logf(s) - lt;
    }

    // acc is wave-uniform after the butterflies
    __shared__ float part[WPB];
    if (lane == 0) part[wib] = acc;
    __syncthreads();
    if (threadIdx.x == 0)
        partial[blockIdx.x] = part[0] + part[1] + part[2] + part[3];
}

__global__ __launch_bounds__(256)
void nll_final(const float* __restrict__ partial, float* __restrict__ out)
{
    float s = 0.0f;
    for (int i = threadIdx.x; i < BLOCKS; i += 256) s += partial[i];
    #pragma unroll
    for (int off = 32; off >= 1; off >>= 1) s += __shfl_xor(s, off, 64);

    __shared__ float wsum[4];
    const int lane = threadIdx.x & 63;
    const int wib  = threadIdx.x >> 6;
    if (lane == 0) wsum[wib] = s;
    __syncthreads();
    if (threadIdx.x == 0)
        out[0] = wsum[0] + wsum[1] + wsum[2] + wsum[3]
               + (float)B * logf((float)V);   // nll0 = B * log(V)
}

extern "C" void kernel_launch(void* const* d_in, const int* in_sizes, int n_in,
                              void* d_out, int out_size, void* d_ws, size_t ws_size,
                              hipStream_t stream)
{
    const int*   seq  = (const int*)d_in[0];
    const float* sim  = (const float*)d_in[1];
    const float* pers = (const float*)d_in[2];
    const float* wts  = (const float*)d_in[3];
    float* partial = (float*)d_ws;            // 624 floats of scratch
    float* out     = (float*)d_out;

    nll_main<<<BLOCKS, 256, 0, stream>>>(seq, sim, pers, wts, partial);
    nll_final<<<1, 256, 0, stream>>>(partial, out);
}